// Round 7
// baseline (184.338 us; speedup 1.0000x reference)
//
#include <hip/hip_runtime.h>
#include <hip/hip_bf16.h>
#include <math.h>

typedef __bf16 v8bf __attribute__((ext_vector_type(8)));
typedef __bf16 v4bf __attribute__((ext_vector_type(4)));
typedef short  v4s  __attribute__((ext_vector_type(4)));
typedef float  v4f  __attribute__((ext_vector_type(4)));
typedef unsigned short u16;

static_assert(sizeof(v8bf) == 16, "v8bf must be 16B");

// ---------- helpers ----------
__device__ __forceinline__ u16 f2bf(float f) {
  __hip_bfloat16 h = __float2bfloat16(f);
  return *reinterpret_cast<u16*>(&h);
}
__device__ __forceinline__ v4f mfma16(v8bf a, v8bf b, v4f c) {
  return __builtin_amdgcn_mfma_f32_16x16x32_bf16(a, b, c, 0, 0, 0);
}
// K=16 shape for PV: A = P (in-register from S^T C/D), B = V from LDS b64.
__device__ __forceinline__ v4f mfma16k16(v4bf a, v4bf b, v4f c) {
#if __has_builtin(__builtin_amdgcn_mfma_f32_16x16x16_bf16)
  return __builtin_amdgcn_mfma_f32_16x16x16_bf16(a, b, c, 0, 0, 0);
#else
  union { v4bf f; v4s s; } ua, ub;
  ua.f = a; ub.f = b;
  return __builtin_amdgcn_mfma_f32_16x16x16bf16_1k(ua.s, ub.s, c, 0, 0, 0);
#endif
}
// async global->LDS, 16B per lane; lptr must be wave-uniform base (HW adds lane*16)
__device__ __forceinline__ void async16(const u16* g, u16* l) {
  __builtin_amdgcn_global_load_lds(
      (__attribute__((address_space(1))) void*)(void*)g,
      (__attribute__((address_space(3))) void*)l, 16, 0, 0);
}

// ---------- prep: z<4 -> weight transpose+convert; z==4 -> x f32->bf16 ----------
__global__ void prep(const float* __restrict__ x, const float* __restrict__ Wq,
                     const float* __restrict__ Wk, const float* __restrict__ Wv,
                     const float* __restrict__ Wo, u16* __restrict__ Wt,
                     u16* __restrict__ xb) {
  int tx = threadIdx.x, ty = threadIdx.y;
  if (blockIdx.z == 4) {  // convert x: 1024 threads x 4 f32 per block
    int bid = blockIdx.y * 32 + blockIdx.x;
    int i = (bid * 1024 + ty * 32 + tx) * 4;
    float4 v = *(const float4*)(x + i);
    ushort4 o;
    o.x = f2bf(v.x); o.y = f2bf(v.y); o.z = f2bf(v.z); o.w = f2bf(v.w);
    *(ushort4*)(xb + i) = o;
    return;
  }
  __shared__ float tile[32][33];
  const float* src = (blockIdx.z == 0) ? Wq : (blockIdx.z == 1) ? Wk : (blockIdx.z == 2) ? Wv : Wo;
  int k0 = blockIdx.x * 32, n0 = blockIdx.y * 32;
  tile[ty][tx] = src[(size_t)(k0 + ty) * 1024 + n0 + tx];
  __syncthreads();
  Wt[(size_t)(blockIdx.z * 1024 + n0 + ty) * 1024 + k0 + tx] = f2bf(tile[tx][ty]);
}

// ---------- shared GEMM mainloop v4: BK=32, 4-buffer counted-vmcnt pipeline ----------
// C[128x128] = A[128xK] * Bt[128xK]^T, K=1024. Tile/LDS-read layout = r0's
// proven structure (64B rows, zero-ish conflicts). NEW: the attn-v7-verified
// T3+T4 skeleton — 4 LDS buffer sets, STAGE(it+2) issued before ONE s_barrier
// per iter, lgkmcnt(0) + counted vmcnt(8/4/0) so 2 stage-sets stay in flight
// ACROSS barriers. r2's failure drained vmcnt(0) per tile (m233's 72% stall);
// this never drains below 8 until the epilogue.
// Hazards (attn v7 invariants): buf (it+2)&3 last read at compute(it-2);
// every wave passed barrier(it-1) after lgkmcnt(0)-draining those reads ->
// overwrite safe. Per-wave vmcnt(<=8) before barrier(it) -> its set(it)
// landed; barrier -> ALL waves' set(it) landed before any compute(it) read.
__device__ __forceinline__ void gemm_core(const u16* __restrict__ A, const u16* __restrict__ Bt,
                                          u16* sA, u16* sB, v4f acc[4][4], int bm, int bn) {
  const int t = threadIdx.x;
  const int w = t >> 6, l = t & 63;
  const int quad = l >> 4, low = l & 15;
  const int wm = (w & 1) * 64, wn = (w >> 1) * 64;
  const int rowA = bm * 128 + w * 32 + (l >> 2);
  const int rowB = bn * 128 + w * 32 + (l >> 2);
  const int col8 = (l & 3) * 8;

  auto STAGE = [&](int kb, int bi) {
    u16* la = sA + bi * 4096 + w * 1024;  // wave-uniform LDS base
    u16* lb = sB + bi * 4096 + w * 1024;
    async16(A + (size_t)rowA * 1024 + kb + col8, la);
    async16(A + (size_t)(rowA + 16) * 1024 + kb + col8, la + 512);
    async16(Bt + (size_t)rowB * 1024 + kb + col8, lb);
    async16(Bt + (size_t)(rowB + 16) * 1024 + kb + col8, lb + 512);
  };

  STAGE(0, 0);
  STAGE(32, 1);
  for (int it = 0; it < 32; ++it) {
    const int bi = it & 3;
    if (it + 2 < 32) STAGE((it + 2) * 32, (it + 2) & 3);
    // my ds_reads of iter it-1 complete before anyone may overwrite that buf
    asm volatile("s_waitcnt lgkmcnt(0)" ::: "memory");
    // my stage-set(it) landed: sets it+1, it+2 (4 ops each) may stay in flight
    const int c = 31 - it;
    if (c >= 2)      asm volatile("s_waitcnt vmcnt(8)" ::: "memory");
    else if (c == 1) asm volatile("s_waitcnt vmcnt(4)" ::: "memory");
    else             asm volatile("s_waitcnt vmcnt(0)" ::: "memory");
    __builtin_amdgcn_s_barrier();   // => ALL waves' set(it) landed, it-1 reads done

    const u16* pa = sA + bi * 4096;
    const u16* pb = sB + bi * 4096;
    v8bf af[4], bfr[4];
#pragma unroll
    for (int i = 0; i < 4; i++)
      af[i] = *(const v8bf*)(pa + (wm + i * 16 + low) * 32 + quad * 8);
#pragma unroll
    for (int j = 0; j < 4; j++)
      bfr[j] = *(const v8bf*)(pb + (wn + j * 16 + low) * 32 + quad * 8);
    __builtin_amdgcn_s_setprio(1);
#pragma unroll
    for (int i = 0; i < 4; i++)
#pragma unroll
      for (int j = 0; j < 4; j++)
        acc[i][j] = mfma16(af[i], bfr[j], acc[i][j]);
    __builtin_amdgcn_s_setprio(0);
  }
}

// ---------- GEMM1: [Qb | Kb | Vt] = xb[4096][1024] @ Wqkv ----------
// Q pre-scaled by 1/8*log2e; V written directly transposed into Vt[b*1024+d][s].
__global__ __launch_bounds__(256) void gemm_qkv(const u16* __restrict__ xb,
                                                const u16* __restrict__ Wt,
                                                u16* __restrict__ Qb,
                                                u16* __restrict__ Kb,
                                                u16* __restrict__ Vt) {
  __shared__ __align__(16) u16 sA[4 * 128 * 32];   // 32 KB
  __shared__ __align__(16) u16 sB[4 * 128 * 32];   // 32 KB
  v4f acc[4][4] = {};
  const int bm = blockIdx.x, bn = blockIdx.y;
  gemm_core(xb, Wt, sA, sB, acc, bm, bn);
  const int t = threadIdx.x, w = t >> 6, l = t & 63, quad = l >> 4, low = l & 15;
  const int wm = (w & 1) * 64, wn = (w >> 1) * 64;
  const int zone = (bn * 128) >> 10;  // 0=Q 1=K 2=V, uniform per block
  const float qsc = (zone == 0) ? 0.18033688011112042f : 1.0f;
#pragma unroll
  for (int i = 0; i < 4; i++) {
    int m0 = bm * 128 + wm + i * 16 + quad * 4;
#pragma unroll
    for (int j = 0; j < 4; j++) {
      int nn = (bn * 128 + wn + j * 16 + low) & 1023;
      if (zone == 0) {
#pragma unroll
        for (int r = 0; r < 4; r++)
          Qb[(size_t)(m0 + r) * 1024 + nn] = f2bf(acc[i][j][r] * qsc);
      } else if (zone == 1) {
#pragma unroll
        for (int r = 0; r < 4; r++)
          Kb[(size_t)(m0 + r) * 1024 + nn] = f2bf(acc[i][j][r]);
      } else {
        int bb = m0 >> 11, s = m0 & 2047;  // m0..m0+3 stay within one batch
#pragma unroll
        for (int r = 0; r < 4; r++)
          Vt[(size_t)(bb * 1024 + nn) * 2048 + s + r] = f2bf(acc[i][j][r]);
      }
    }
  }
}

// ---------- GEMM2: out[4096][1024] = ctx @ Wo + bo, f32 out ----------
// Same counted-vmcnt 4-buffer pipeline; 3 staging loads per set -> vmcnt(6/3/0).
__global__ __launch_bounds__(256) void gemm_out(const u16* __restrict__ ctx,
                                                const u16* __restrict__ Wt,
                                                const float* __restrict__ bo,
                                                float* __restrict__ out) {
  __shared__ __align__(16) u16 sA[4 * 128 * 32];   // 32 KB
  __shared__ __align__(16) u16 sB[4 * 64 * 32];    // 16 KB
  const u16* Bt = Wt + (size_t)3072 * 1024;
  v4f acc[4][2] = {};
  const int bm = blockIdx.x, bn = blockIdx.y;
  const int t = threadIdx.x, w = t >> 6, l = t & 63, quad = l >> 4, low = l & 15;
  const int wm = (w & 1) * 64, wn = (w >> 1) * 32;
  const int rowA = bm * 128 + w * 32 + (l >> 2);
  const int rowB = bn * 64 + w * 16 + (l >> 2);
  const int col8 = (l & 3) * 8;

  auto STAGE = [&](int kb, int bi) {
    u16* la = sA + bi * 4096 + w * 1024;
    u16* lb = sB + bi * 2048 + w * 512;
    async16(ctx + (size_t)rowA * 1024 + kb + col8, la);
    async16(ctx + (size_t)(rowA + 16) * 1024 + kb + col8, la + 512);
    async16(Bt + (size_t)rowB * 1024 + kb + col8, lb);
  };

  STAGE(0, 0);
  STAGE(32, 1);
  for (int it = 0; it < 32; ++it) {
    const int bi = it & 3;
    if (it + 2 < 32) STAGE((it + 2) * 32, (it + 2) & 3);
    asm volatile("s_waitcnt lgkmcnt(0)" ::: "memory");
    const int c = 31 - it;
    if (c >= 2)      asm volatile("s_waitcnt vmcnt(6)" ::: "memory");
    else if (c == 1) asm volatile("s_waitcnt vmcnt(3)" ::: "memory");
    else             asm volatile("s_waitcnt vmcnt(0)" ::: "memory");
    __builtin_amdgcn_s_barrier();

    const u16* pa = sA + bi * 4096;
    const u16* pb = sB + bi * 2048;
    v8bf af[4], bfr[2];
#pragma unroll
    for (int i = 0; i < 4; i++)
      af[i] = *(const v8bf*)(pa + (wm + i * 16 + low) * 32 + quad * 8);
#pragma unroll
    for (int j = 0; j < 2; j++)
      bfr[j] = *(const v8bf*)(pb + (wn + j * 16 + low) * 32 + quad * 8);
    __builtin_amdgcn_s_setprio(1);
#pragma unroll
    for (int i = 0; i < 4; i++)
#pragma unroll
      for (int j = 0; j < 2; j++)
        acc[i][j] = mfma16(af[i], bfr[j], acc[i][j]);
    __builtin_amdgcn_s_setprio(0);
  }
#pragma unroll
  for (int i = 0; i < 4; i++) {
    int m0 = bm * 128 + wm + i * 16 + quad * 4;
#pragma unroll
    for (int j = 0; j < 2; j++) {
      int n = bn * 64 + wn + j * 16 + low;
      float bias = bo[n];
#pragma unroll
      for (int r = 0; r < 4; r++)
        out[(size_t)(m0 + r) * 1024 + n] = acc[i][j][r] + bias;
    }
  }
}

// ---------- flash attention v7 (r1-exact: best measured total config) ----------
//  1. Uniform work: complementary q-tile pair (31-tp, tp) -> 33 k-iters/block.
//  2. XCD locality (T1): 4 (b,h) pairs pinned per XCD -> K/V L2-resident.
//  3. Counted-vmcnt pipeline (T3+T4): 4 LDS buffers, 2-deep prefetch.
//  4. s_setprio(1) around MFMA clusters (T5).
__global__ __launch_bounds__(256) void attn(const u16* __restrict__ Qb,
                                            const u16* __restrict__ Kb,
                                            const u16* __restrict__ Vt,
                                            u16* __restrict__ ctx) {
  __shared__ __align__(16) u16 sK[4][4096];   // [key][64 d] swizzled, 8KB per buf
  __shared__ __align__(16) u16 sV[4][4096];   // [d][64 keys] swizzled
  const int t = threadIdx.x, w = t >> 6, l = t & 63, quad = l >> 4, low = l & 15;

  const int bid = blockIdx.x;          // 0..511
  const int xcd = bid & 7, slot = bid >> 3;      // slot 0..63
  const int pair = xcd * 4 + (slot & 3);         // (b,h) pair pinned to this XCD
  const int tp = slot >> 2;                      // 0..15: q-tile pair index
  const int b = pair >> 4, h = pair & 15;

  const u16* kbase = Kb + (size_t)(b * 2048) * 1024 + h * 64;   // + key*1024
  const u16* vbase = Vt + (size_t)(b * 1024 + h * 64) * 2048;   // + d*2048 + s

  // staging lane constants: row = w*8 + srow (+32), swizzled chunk cg
  const int srow = l >> 3;
  const int cg = (l & 7) ^ srow;

  auto STAGE = [&](int tt, int bi) {
    const int kb = tt * 64;
    const u16* kg = kbase + (size_t)(kb + w * 8 + srow) * 1024 + cg * 8;
    async16(kg, &sK[bi][w * 512]);
    async16(kg + (size_t)32 * 1024, &sK[bi][2048 + w * 512]);
    const u16* vg = vbase + (size_t)(w * 8 + srow) * 2048 + kb + cg * 8;
    async16(vg, &sV[bi][w * 512]);
    async16(vg + (size_t)32 * 2048, &sV[bi][2048 + w * 512]);
  };

  for (int ph = 0; ph < 2; ++ph) {
    const int tile = ph ? tp : 31 - tp;   // heavy tile first: phase-1 K/V prefix is L2-warm
    const int nkt = tile + 1;
    const int qw = tile * 64 + w * 16;

    if (ph) {  // all waves done reading phase-0 buffers before restaging
      asm volatile("s_waitcnt lgkmcnt(0)" ::: "memory");
      __builtin_amdgcn_s_barrier();
    }

    // Q fragments (B-operand for S^T). Loaded BEFORE any STAGE so the manual
    // vmcnt counts below stay exact; the empty asm pins issue order.
    const u16* qrow_p = Qb + (size_t)(b * 2048 + qw + low) * 1024 + h * 64;
    v8bf qa0 = *(const v8bf*)(qrow_p + quad * 8);
    v8bf qa1 = *(const v8bf*)(qrow_p + 32 + quad * 8);
    asm volatile("" ::: "memory");

    float li = 0.f;
    v4f o[4] = {};

    STAGE(0, 0);
    if (nkt > 1) STAGE(1, 1);

    for (int it = 0; it < nkt; ++it) {
      const int bi = it & 3;
      // 2-deep prefetch: buf (it+2)&3 was last read at iter it-2; every wave
      // drained lgkmcnt before barrier(it-1), so the overwrite is safe.
      if (it + 2 < nkt) STAGE(it + 2, (it + 2) & 3);
      // my ds_reads of iter it-1 complete (MFMAs may have sunk past barriers)
      asm volatile("s_waitcnt lgkmcnt(0)" ::: "memory");
      // my stage-set P(it) landed: exactly 4*c younger vmem ops outstanding
      const int c = nkt - 1 - it;
      if (c >= 2)      asm volatile("s_waitcnt vmcnt(8)" ::: "memory");
      else if (c == 1) asm volatile("s_waitcnt vmcnt(4)" ::: "memory");
      else             asm volatile("s_waitcnt vmcnt(0)" ::: "memory");
      __builtin_amdgcn_s_barrier();   // => ALL waves' P(it) landed, it-1 reads done

      const int kb = it * 64;
      // S^T = K Q^T : 4 key-frags (A=K, m=key) x 2 d-slices; B=Q shared
      v4f s[4] = {};
      __builtin_amdgcn_s_setprio(1);
#pragma unroll
      for (int cf = 0; cf < 4; cf++) {
        const int key = cf * 16 + low;
        v8bf kf0 = *(const v8bf*)(&sK[bi][key * 64 + ((quad ^ (key & 7)) * 8)]);
        v8bf kf1 = *(const v8bf*)(&sK[bi][key * 64 + (((4 + quad) ^ (key & 7)) * 8)]);
        s[cf] = mfma16(kf0, qa0, s[cf]);
        s[cf] = mfma16(kf1, qa1, s[cf]);
      }
      __builtin_amdgcn_s_setprio(0);

      // exp + lane-local denominator; P packed in-register as PV A-frags
      const bool dm = (it == nkt - 1);
      const int qr = qw + low;
      v4bf pf[4];
#pragma unroll
      for (int cf = 0; cf < 4; cf++)
#pragma unroll
        for (int r = 0; r < 4; r++) {
          float e = __builtin_amdgcn_exp2f(s[cf][r]);
          if (dm && (kb + cf * 16 + quad * 4 + r > qr)) e = 0.f;
          li += e;
          pf[cf][r] = (__bf16)e;
        }

      // PV: o[q][d] += P·V via K=16 MFMAs; B = V[key][d] read as ds_read_b64
      __builtin_amdgcn_s_setprio(1);
#pragma unroll
      for (int df = 0; df < 4; df++) {
        const int d = df * 16 + low;
#pragma unroll
        for (int cf = 0; cf < 4; cf++) {
          const int c2 = cf * 2 + (quad >> 1);
          const v4bf vf = *(const v4bf*)(&sV[bi][d * 64 + ((c2 ^ (d & 7)) * 8) + (quad & 1) * 4]);
          o[df] = mfma16k16(pf[cf], vf, o[df]);
        }
      }
      __builtin_amdgcn_s_setprio(0);
    }

    // denominator: li(lane) covers qrow qw+low after reducing across quads
    li += __shfl_xor(li, 16);
    li += __shfl_xor(li, 32);

    // epilogue: o C/D rows = qw+quad*4+r, cols = df*16+low
#pragma unroll
    for (int r = 0; r < 4; r++) {
      float lir = __shfl(li, quad * 4 + r);
      float inv = 1.f / lir;
      int row = b * 2048 + qw + quad * 4 + r;
#pragma unroll
      for (int df = 0; df < 4; df++)
        ctx[(size_t)row * 1024 + h * 64 + df * 16 + low] = f2bf(o[df][r] * inv);
    }
  }
}

// ---------- launch ----------
extern "C" void kernel_launch(void* const* d_in, const int* in_sizes, int n_in,
                              void* d_out, int out_size, void* d_ws, size_t ws_size,
                              hipStream_t stream) {
  const float* x  = (const float*)d_in[0];
  const float* Wq = (const float*)d_in[1];
  const float* Wk = (const float*)d_in[2];
  const float* Wv = (const float*)d_in[3];
  const float* Wo = (const float*)d_in[4];
  const float* bo = (const float*)d_in[5];
  float* out = (float*)d_out;

  char* ws = (char*)d_ws;
  u16* xb  = (u16*)(ws);                          // [4096][1024] bf16 = 8 MB
  u16* Wt  = (u16*)(ws + 8ull * 1024 * 1024);     // [4096][1024] bf16 = 8 MB
  u16* Qb  = (u16*)(ws + 16ull * 1024 * 1024);    // [4096][1024] bf16 = 8 MB (pre-scaled)
  u16* Kb  = (u16*)(ws + 24ull * 1024 * 1024);    // [4096][1024] bf16 = 8 MB
  u16* Vt  = (u16*)(ws + 32ull * 1024 * 1024);    // [2*1024][2048] bf16 = 8 MB
  u16* ctx = (u16*)(ws + 40ull * 1024 * 1024);    // [4096][1024] bf16 = 8 MB

  prep<<<dim3(32, 32, 5), dim3(32, 32, 1), 0, stream>>>(x, Wq, Wk, Wv, Wo, Wt, xb);
  gemm_qkv<<<dim3(32, 24, 1), dim3(256, 1, 1), 0, stream>>>(xb, Wt, Qb, Kb, Vt);
  attn<<<dim3(512, 1, 1), dim3(256, 1, 1), 0, stream>>>(Qb, Kb, Vt, ctx);
  gemm_out<<<dim3(32, 16, 1), dim3(256, 1, 1), 0, stream>>>(ctx, Wt, bo, out);
}

// Round 8
// 175.675 us; speedup vs baseline: 1.0493x; 1.0493x over previous
//
#include <hip/hip_runtime.h>
#include <hip/hip_bf16.h>
#include <math.h>

typedef __bf16 v8bf __attribute__((ext_vector_type(8)));
typedef __bf16 v4bf __attribute__((ext_vector_type(4)));
typedef short  v4s  __attribute__((ext_vector_type(4)));
typedef float  v4f  __attribute__((ext_vector_type(4)));
typedef unsigned short u16;

static_assert(sizeof(v8bf) == 16, "v8bf must be 16B");

// ---------- helpers ----------
__device__ __forceinline__ u16 f2bf(float f) {
  __hip_bfloat16 h = __float2bfloat16(f);
  return *reinterpret_cast<u16*>(&h);
}
__device__ __forceinline__ v4f mfma16(v8bf a, v8bf b, v4f c) {
  return __builtin_amdgcn_mfma_f32_16x16x32_bf16(a, b, c, 0, 0, 0);
}
// K=16 shape for PV: A = P (in-register from S^T C/D), B = V from LDS b64.
__device__ __forceinline__ v4f mfma16k16(v4bf a, v4bf b, v4f c) {
#if __has_builtin(__builtin_amdgcn_mfma_f32_16x16x16_bf16)
  return __builtin_amdgcn_mfma_f32_16x16x16_bf16(a, b, c, 0, 0, 0);
#else
  union { v4bf f; v4s s; } ua, ub;
  ua.f = a; ub.f = b;
  return __builtin_amdgcn_mfma_f32_16x16x16bf16_1k(ua.s, ub.s, c, 0, 0, 0);
#endif
}
// async global->LDS, 16B per lane; lptr must be wave-uniform base (HW adds lane*16)
__device__ __forceinline__ void async16(const u16* g, u16* l) {
  __builtin_amdgcn_global_load_lds(
      (__attribute__((address_space(1))) void*)(void*)g,
      (__attribute__((address_space(3))) void*)l, 16, 0, 0);
}

// ---------- prep: z<4 -> weight transpose+convert; z==4 -> x f32->bf16 ----------
__global__ void prep(const float* __restrict__ x, const float* __restrict__ Wq,
                     const float* __restrict__ Wk, const float* __restrict__ Wv,
                     const float* __restrict__ Wo, u16* __restrict__ Wt,
                     u16* __restrict__ xb) {
  int tx = threadIdx.x, ty = threadIdx.y;
  if (blockIdx.z == 4) {  // convert x: 1024 threads x 4 f32 per block
    int bid = blockIdx.y * 32 + blockIdx.x;
    int i = (bid * 1024 + ty * 32 + tx) * 4;
    float4 v = *(const float4*)(x + i);
    ushort4 o;
    o.x = f2bf(v.x); o.y = f2bf(v.y); o.z = f2bf(v.z); o.w = f2bf(v.w);
    *(ushort4*)(xb + i) = o;
    return;
  }
  __shared__ float tile[32][33];
  const float* src = (blockIdx.z == 0) ? Wq : (blockIdx.z == 1) ? Wk : (blockIdx.z == 2) ? Wv : Wo;
  int k0 = blockIdx.x * 32, n0 = blockIdx.y * 32;
  tile[ty][tx] = src[(size_t)(k0 + ty) * 1024 + n0 + tx];
  __syncthreads();
  Wt[(size_t)(blockIdx.z * 1024 + n0 + ty) * 1024 + k0 + tx] = f2bf(tile[tx][ty]);
}

// ---------- GEMM1 v5: 256x256 tile, 8 waves, BK=64, 2-dbuf 128KB LDS ----------
// 8-phase-family schedule (T2+T3+T4+T5 co-designed; regime-gate: this ONLY
// works at 256²/8-wave — r2/r6/r7 proved every pipelining attempt at 128²
// loses to plain TLP).
// Derived schedule, per K-tile kt (4 phases, 16 MFMA each, per wave):
//   stage order for tile kt+1 (2 async16-calls/phase, into the OTHER buffer):
//     ph0: B[0..63], B[64..127]; ph1: B[128..191], B[192..255];
//     ph2: A[0..63], A[128..191]; ph3: A[64..127], A[192..255]
//   consumption: ph p reads A rows wm+p*32..+31 (+ ph0: all of the wave's B
//   rows) -> at the tile boundary only the 2 newest staged chunks (A[64..],
//   A[192..]) are still allowed in flight (vmcnt(2)): they are first needed
//   at ph2, published by a mid-tile vmcnt(4)+barrier. The vmem queue never
//   drains in steady state; 32 MFMA per barrier, 2 barriers per K-tile.
// Cross-wave safety: boundary barrier follows lgkmcnt(0) (all my reads of the
// buffer being restaged are done) + vmcnt(2) (my slices of stage(kt) landed);
// barrier publishes both to all waves. Mid barrier publishes the last 2 chunks.
// LDS reads use the r6-VERIFIED XOR-chunk swizzle (0 conflicts measured):
// physical chunk = logical ^ (row&7); staging pre-swizzles the global source
// (rule #21 both-sides).
__global__ __launch_bounds__(512) void gemm_qkv(const u16* __restrict__ xb,
                                                const u16* __restrict__ Wt,
                                                u16* __restrict__ Qb,
                                                u16* __restrict__ Kb,
                                                u16* __restrict__ Vt) {
  extern __shared__ __align__(16) u16 lds[];   // 131072 B
  u16* sA = lds;           // [2][256*64]
  u16* sB = lds + 32768;   // [2][256*64]

  const int t = threadIdx.x;
  const int w = t >> 6, l = t & 63;
  const int quad = l >> 4, low = l & 15;
  const int wm = (w & 1) * 128, wn = (w >> 1) * 64;
  const int bm = blockIdx.x, bn = blockIdx.y;

  // staging lane constants (r6-verified): 8 rows/wave/call, chunk pre-swizzle
  const int srow = l >> 3;
  const int cg = (l & 7) ^ srow;

  auto SA_ = [&](int R0, int kb, u16* dst) {
    async16(xb + (size_t)(bm * 256 + R0 + w * 8 + srow) * 1024 + kb + cg * 8,
            dst + (R0 + w * 8) * 64);
  };
  auto SB_ = [&](int R0, int kb, u16* dst) {
    async16(Wt + (size_t)(bn * 256 + R0 + w * 8 + srow) * 1024 + kb + cg * 8,
            dst + (R0 + w * 8) * 64);
  };

  v4f acc[8][4] = {};

  // prologue: stage tile 0 into buf 0 in the canonical order
  SB_(0, 0, sB); SB_(64, 0, sB); SB_(128, 0, sB); SB_(192, 0, sB);
  SA_(0, 0, sA); SA_(128, 0, sA); SA_(64, 0, sA); SA_(192, 0, sA);

#pragma unroll 2
  for (int kt = 0; kt < 16; ++kt) {
    const int p = kt & 1;
    const u16* pa = sA + p * 16384;
    const u16* pb = sB + p * 16384;
    u16* nA = sA + (p ^ 1) * 16384;
    u16* nB = sB + (p ^ 1) * 16384;
    const int nkb = (kt + 1) * 64;
    const bool more = (kt < 15);

    // ---- K-tile boundary ----
    asm volatile("s_waitcnt lgkmcnt(0)" ::: "memory");  // my reads of buf being restaged done
    asm volatile("s_waitcnt vmcnt(2)" ::: "memory");    // stage(kt) landed except 2 newest A-chunks
    __builtin_amdgcn_s_barrier();

    // phase 0: load all B-frags + A m-frags 0,1; stage B'[0],B'[64]
    v8bf bf[2][4];
#pragma unroll
    for (int j = 0; j < 4; j++) {
      const int rb = wn + j * 16 + low, sw = rb & 7;
      bf[0][j] = *(const v8bf*)(pb + rb * 64 + ((quad ^ sw) * 8));
      bf[1][j] = *(const v8bf*)(pb + rb * 64 + (((4 + quad) ^ sw) * 8));
    }
#pragma unroll
    for (int ph = 0; ph < 4; ++ph) {
      if (ph == 2) {   // mid-tile: publish the 2 newest A-chunks of stage(kt)
        if (more) asm volatile("s_waitcnt vmcnt(4)" ::: "memory");
        else      asm volatile("s_waitcnt vmcnt(0)" ::: "memory");
        __builtin_amdgcn_s_barrier();
      }
      v8bf a0k0, a0k1, a1k0, a1k1;
      {
        const int ra = wm + (2 * ph) * 16 + low, sw = ra & 7;
        a0k0 = *(const v8bf*)(pa + ra * 64 + ((quad ^ sw) * 8));
        a0k1 = *(const v8bf*)(pa + ra * 64 + (((4 + quad) ^ sw) * 8));
      }
      {
        const int ra = wm + (2 * ph + 1) * 16 + low, sw = ra & 7;
        a1k0 = *(const v8bf*)(pa + ra * 64 + ((quad ^ sw) * 8));
        a1k1 = *(const v8bf*)(pa + ra * 64 + (((4 + quad) ^ sw) * 8));
      }
      if (more) {
        if (ph == 0)      { SB_(0, nkb, nB);   SB_(64, nkb, nB); }
        else if (ph == 1) { SB_(128, nkb, nB); SB_(192, nkb, nB); }
        else if (ph == 2) { SA_(0, nkb, nA);   SA_(128, nkb, nA); }
        else              { SA_(64, nkb, nA);  SA_(192, nkb, nA); }
      }
      __builtin_amdgcn_s_setprio(1);
#pragma unroll
      for (int j = 0; j < 4; j++) {
        acc[2 * ph][j]     = mfma16(a0k0, bf[0][j], acc[2 * ph][j]);
        acc[2 * ph][j]     = mfma16(a0k1, bf[1][j], acc[2 * ph][j]);
        acc[2 * ph + 1][j] = mfma16(a1k0, bf[0][j], acc[2 * ph + 1][j]);
        acc[2 * ph + 1][j] = mfma16(a1k1, bf[1][j], acc[2 * ph + 1][j]);
      }
      __builtin_amdgcn_s_setprio(0);
    }
  }

  // ---- epilogue: zones are 1024-wide; 256 | 1024 so zone uniform per block
  const int zone = bn >> 2;   // 0=Q 1=K 2=V
  const float qsc = (zone == 0) ? 0.18033688011112042f : 1.0f;
#pragma unroll
  for (int i = 0; i < 8; i++) {
    int m0 = bm * 256 + wm + i * 16 + quad * 4;
#pragma unroll
    for (int j = 0; j < 4; j++) {
      int nn = (bn * 256 + wn + j * 16 + low) & 1023;
      if (zone == 0) {
#pragma unroll
        for (int r = 0; r < 4; r++)
          Qb[(size_t)(m0 + r) * 1024 + nn] = f2bf(acc[i][j][r] * qsc);
      } else if (zone == 1) {
#pragma unroll
        for (int r = 0; r < 4; r++)
          Kb[(size_t)(m0 + r) * 1024 + nn] = f2bf(acc[i][j][r]);
      } else {
        int bb = m0 >> 11, s = m0 & 2047;  // m0..m0+3 stay within one batch
#pragma unroll
        for (int r = 0; r < 4; r++)
          Vt[(size_t)(bb * 1024 + nn) * 2048 + s + r] = f2bf(acc[i][j][r]);
      }
    }
  }
}

// ---------- GEMM2: out[4096][1024] = ctx @ Wo + bo, f32 out (r0 structure) ----------
__global__ __launch_bounds__(256) void gemm_out(const u16* __restrict__ ctx,
                                                const u16* __restrict__ Wt,
                                                const float* __restrict__ bo,
                                                float* __restrict__ out) {
  __shared__ __align__(16) u16 sA[128 * 32];
  __shared__ __align__(16) u16 sB[64 * 32];
  const u16* Bt = Wt + (size_t)3072 * 1024;
  v4f acc[4][2] = {};
  const int bm = blockIdx.x, bn = blockIdx.y;
  const int t = threadIdx.x, w = t >> 6, l = t & 63, quad = l >> 4, low = l & 15;
  const int wm = (w & 1) * 64, wn = (w >> 1) * 32;
  const int rowA = bm * 128 + w * 32 + (l >> 2);
  const int rowB = bn * 64 + w * 16 + (l >> 2);
  const int col8 = (l & 3) * 8;
  u16* la = sA + w * 1024;
  u16* lb = sB + w * 512;

  for (int kb = 0; kb < 1024; kb += 32) {
    async16(ctx + (size_t)rowA * 1024 + kb + col8, la);
    async16(ctx + (size_t)(rowA + 16) * 1024 + kb + col8, la + 512);
    async16(Bt + (size_t)rowB * 1024 + kb + col8, lb);
    __syncthreads();
    v8bf af[4], bfr[2];
#pragma unroll
    for (int i = 0; i < 4; i++)
      af[i] = *(const v8bf*)(sA + (wm + i * 16 + low) * 32 + quad * 8);
#pragma unroll
    for (int j = 0; j < 2; j++)
      bfr[j] = *(const v8bf*)(sB + (wn + j * 16 + low) * 32 + quad * 8);
#pragma unroll
    for (int i = 0; i < 4; i++)
#pragma unroll
      for (int j = 0; j < 2; j++)
        acc[i][j] = mfma16(af[i], bfr[j], acc[i][j]);
    __syncthreads();
  }
#pragma unroll
  for (int i = 0; i < 4; i++) {
    int m0 = bm * 128 + wm + i * 16 + quad * 4;
#pragma unroll
    for (int j = 0; j < 2; j++) {
      int n = bn * 64 + wn + j * 16 + low;
      float bias = bo[n];
#pragma unroll
      for (int r = 0; r < 4; r++)
        out[(size_t)(m0 + r) * 1024 + n] = acc[i][j][r] + bias;
    }
  }
}

// ---------- flash attention v7 (r1-exact: best measured total config) ----------
__global__ __launch_bounds__(256) void attn(const u16* __restrict__ Qb,
                                            const u16* __restrict__ Kb,
                                            const u16* __restrict__ Vt,
                                            u16* __restrict__ ctx) {
  __shared__ __align__(16) u16 sK[4][4096];   // [key][64 d] swizzled, 8KB per buf
  __shared__ __align__(16) u16 sV[4][4096];   // [d][64 keys] swizzled
  const int t = threadIdx.x, w = t >> 6, l = t & 63, quad = l >> 4, low = l & 15;

  const int bid = blockIdx.x;          // 0..511
  const int xcd = bid & 7, slot = bid >> 3;      // slot 0..63
  const int pair = xcd * 4 + (slot & 3);         // (b,h) pair pinned to this XCD
  const int tp = slot >> 2;                      // 0..15: q-tile pair index
  const int b = pair >> 4, h = pair & 15;

  const u16* kbase = Kb + (size_t)(b * 2048) * 1024 + h * 64;   // + key*1024
  const u16* vbase = Vt + (size_t)(b * 1024 + h * 64) * 2048;   // + d*2048 + s

  const int srow = l >> 3;
  const int cg = (l & 7) ^ srow;

  auto STAGE = [&](int tt, int bi) {
    const int kb = tt * 64;
    const u16* kg = kbase + (size_t)(kb + w * 8 + srow) * 1024 + cg * 8;
    async16(kg, &sK[bi][w * 512]);
    async16(kg + (size_t)32 * 1024, &sK[bi][2048 + w * 512]);
    const u16* vg = vbase + (size_t)(w * 8 + srow) * 2048 + kb + cg * 8;
    async16(vg, &sV[bi][w * 512]);
    async16(vg + (size_t)32 * 2048, &sV[bi][2048 + w * 512]);
  };

  for (int ph = 0; ph < 2; ++ph) {
    const int tile = ph ? tp : 31 - tp;   // heavy tile first: phase-1 K/V prefix is L2-warm
    const int nkt = tile + 1;
    const int qw = tile * 64 + w * 16;

    if (ph) {  // all waves done reading phase-0 buffers before restaging
      asm volatile("s_waitcnt lgkmcnt(0)" ::: "memory");
      __builtin_amdgcn_s_barrier();
    }

    const u16* qrow_p = Qb + (size_t)(b * 2048 + qw + low) * 1024 + h * 64;
    v8bf qa0 = *(const v8bf*)(qrow_p + quad * 8);
    v8bf qa1 = *(const v8bf*)(qrow_p + 32 + quad * 8);
    asm volatile("" ::: "memory");

    float li = 0.f;
    v4f o[4] = {};

    STAGE(0, 0);
    if (nkt > 1) STAGE(1, 1);

    for (int it = 0; it < nkt; ++it) {
      const int bi = it & 3;
      if (it + 2 < nkt) STAGE(it + 2, (it + 2) & 3);
      asm volatile("s_waitcnt lgkmcnt(0)" ::: "memory");
      const int c = nkt - 1 - it;
      if (c >= 2)      asm volatile("s_waitcnt vmcnt(8)" ::: "memory");
      else if (c == 1) asm volatile("s_waitcnt vmcnt(4)" ::: "memory");
      else             asm volatile("s_waitcnt vmcnt(0)" ::: "memory");
      __builtin_amdgcn_s_barrier();

      const int kb = it * 64;
      v4f s[4] = {};
      __builtin_amdgcn_s_setprio(1);
#pragma unroll
      for (int cf = 0; cf < 4; cf++) {
        const int key = cf * 16 + low;
        v8bf kf0 = *(const v8bf*)(&sK[bi][key * 64 + ((quad ^ (key & 7)) * 8)]);
        v8bf kf1 = *(const v8bf*)(&sK[bi][key * 64 + (((4 + quad) ^ (key & 7)) * 8)]);
        s[cf] = mfma16(kf0, qa0, s[cf]);
        s[cf] = mfma16(kf1, qa1, s[cf]);
      }
      __builtin_amdgcn_s_setprio(0);

      const bool dm = (it == nkt - 1);
      const int qr = qw + low;
      v4bf pf[4];
#pragma unroll
      for (int cf = 0; cf < 4; cf++)
#pragma unroll
        for (int r = 0; r < 4; r++) {
          float e = __builtin_amdgcn_exp2f(s[cf][r]);
          if (dm && (kb + cf * 16 + quad * 4 + r > qr)) e = 0.f;
          li += e;
          pf[cf][r] = (__bf16)e;
        }

      __builtin_amdgcn_s_setprio(1);
#pragma unroll
      for (int df = 0; df < 4; df++) {
        const int d = df * 16 + low;
#pragma unroll
        for (int cf = 0; cf < 4; cf++) {
          const int c2 = cf * 2 + (quad >> 1);
          const v4bf vf = *(const v4bf*)(&sV[bi][d * 64 + ((c2 ^ (d & 7)) * 8) + (quad & 1) * 4]);
          o[df] = mfma16k16(pf[cf], vf, o[df]);
        }
      }
      __builtin_amdgcn_s_setprio(0);
    }

    li += __shfl_xor(li, 16);
    li += __shfl_xor(li, 32);

#pragma unroll
    for (int r = 0; r < 4; r++) {
      float lir = __shfl(li, quad * 4 + r);
      float inv = 1.f / lir;
      int row = b * 2048 + qw + quad * 4 + r;
#pragma unroll
      for (int df = 0; df < 4; df++)
        ctx[(size_t)row * 1024 + h * 64 + df * 16 + low] = f2bf(o[df][r] * inv);
    }
  }
}

// ---------- launch ----------
extern "C" void kernel_launch(void* const* d_in, const int* in_sizes, int n_in,
                              void* d_out, int out_size, void* d_ws, size_t ws_size,
                              hipStream_t stream) {
  const float* x  = (const float*)d_in[0];
  const float* Wq = (const float*)d_in[1];
  const float* Wk = (const float*)d_in[2];
  const float* Wv = (const float*)d_in[3];
  const float* Wo = (const float*)d_in[4];
  const float* bo = (const float*)d_in[5];
  float* out = (float*)d_out;

  char* ws = (char*)d_ws;
  u16* xb  = (u16*)(ws);                          // [4096][1024] bf16 = 8 MB
  u16* Wt  = (u16*)(ws + 8ull * 1024 * 1024);     // [4096][1024] bf16 = 8 MB
  u16* Qb  = (u16*)(ws + 16ull * 1024 * 1024);    // [4096][1024] bf16 = 8 MB (pre-scaled)
  u16* Kb  = (u16*)(ws + 24ull * 1024 * 1024);    // [4096][1024] bf16 = 8 MB
  u16* Vt  = (u16*)(ws + 32ull * 1024 * 1024);    // [2*1024][2048] bf16 = 8 MB
  u16* ctx = (u16*)(ws + 40ull * 1024 * 1024);    // [4096][1024] bf16 = 8 MB

  static bool cfg = false;
  if (!cfg) {
    hipFuncSetAttribute((const void*)gemm_qkv,
                        hipFuncAttributeMaxDynamicSharedMemorySize, 131072);
    cfg = true;
  }

  prep<<<dim3(32, 32, 5), dim3(32, 32, 1), 0, stream>>>(x, Wq, Wk, Wv, Wo, Wt, xb);
  gemm_qkv<<<dim3(16, 12, 1), dim3(512, 1, 1), 131072, stream>>>(xb, Wt, Qb, Kb, Vt);
  attn<<<dim3(512, 1, 1), dim3(256, 1, 1), 0, stream>>>(Qb, Kb, Vt, ctx);
  gemm_out<<<dim3(32, 16, 1), dim3(256, 1, 1), 0, stream>>>(ctx, Wt, bo, out);
}